// Round 3
// baseline (379.550 us; speedup 1.0000x reference)
//
#include <hip/hip_runtime.h>
#include <hip/hip_bf16.h>

// LFQ forward fused kernels for MI355X (gfx950).
// Outputs in d_out (float32): out[16384*512], indices[16384] (as float), aux_loss[1]
// ws layout: P[256][4096] partial avg_prob sums (4 MB), then 2 scalars {C_sum, E_sum}

#define NS    16384      // samples = 4*4096
#define NOUT  (NS*512)   // 8388608
#define AUXO  (NOUT+NS)  // 8404992
#define INVT2 200.0f     // 2 * inv_temperature
#define NBLK  256        // K1 blocks; 64 samples each

// -------- K1: xp, indices, out-projection, factorized softmax entropy + avg_prob partials
// LDS = 24 + 24 + 16 + 16 = 80 KB exactly -> 2 blocks/CU.
__global__ __launch_bounds__(512, 4) void k_main(
    const float* __restrict__ x,
    const float* __restrict__ w_in,  const float* __restrict__ b_in,
    const float* __restrict__ w_out, const float* __restrict__ b_out,
    float* __restrict__ out, float* __restrict__ idx_out,
    float* __restrict__ P, float* __restrict__ Csum) {

  __shared__ __align__(16) float s_wi[6144];     // w_in  row-major [d][512]
  __shared__ __align__(16) float s_wt[6144];     // w_out^T row-major [d][512]
  __shared__ __align__(16) float s_phi[64][64];  // rows: first hold xp[12], then phi[64]
  __shared__ __align__(16) float s_psi[64][64];

  const int t = threadIdx.x;

  // stage weights (row-major; new lane mapping is conflict-free without swizzle)
  #pragma unroll
  for (int k = 0; k < 12; ++k) {
    int f = t + k * 512;
    int d = f >> 9, e = f & 511;
    s_wi[f] = w_in[f];             // w_in is [12][512] row-major already
    s_wt[f] = w_out[e * 12 + d];   // transpose of w_out[512][12]
  }
  __syncthreads();

  const int wave = t >> 6, lane = t & 63;
  const int g = lane >> 4, sub = lane & 15;
  const int ibase = blockIdx.x * 64 + wave * 8;

  float bin[12];
  #pragma unroll
  for (int d = 0; d < 12; ++d) bin[d] = b_in[d];

  // ---- Pass A: projection-in, 16 lanes per sample, e = e4*64 + sub*4 (coalesced)
  #pragma unroll 1
  for (int bt = 0; bt < 2; ++bt) {
    const int i = ibase + bt * 4 + g;
    float4 xv[8];
    #pragma unroll
    for (int e4 = 0; e4 < 8; ++e4)
      xv[e4] = *(const float4*)(x + (size_t)i * 512 + e4 * 64 + sub * 4);

    float p[12];
    #pragma unroll
    for (int d = 0; d < 12; ++d) p[d] = 0.f;
    #pragma unroll
    for (int e4 = 0; e4 < 8; ++e4) {
      #pragma unroll
      for (int d = 0; d < 12; ++d) {
        float4 w4 = *(const float4*)&s_wi[d * 512 + e4 * 64 + sub * 4];
        p[d] += xv[e4].x * w4.x + xv[e4].y * w4.y + xv[e4].z * w4.z + xv[e4].w * w4.w;
      }
    }
    #pragma unroll
    for (int d = 0; d < 12; ++d) {
      #pragma unroll
      for (int m = 1; m <= 8; m <<= 1) p[d] += __shfl_xor(p[d], m, 16);
      p[d] += bin[d];
    }

    unsigned idx = 0u;
    #pragma unroll
    for (int d = 0; d < 12; ++d) idx |= (p[d] > 0.f ? 1u : 0u) << (11 - d);
    if (sub == 0) {
      idx_out[i] = (float)idx;
      #pragma unroll
      for (int d = 0; d < 12; ++d) s_phi[wave * 8 + bt * 4 + g][d] = p[d];
    }
    // same-wave LDS write->read below; lockstep + compiler lgkmcnt keeps order
  }

  // ---- Pass B: projection-out, all 64 lanes on one sample; e = 4*lane / 256+4*lane
  // -> two perfectly contiguous 1 KB wave stores per sample
  float4 bo0 = *(const float4*)(b_out + 4 * lane);
  float4 bo1 = *(const float4*)(b_out + 256 + 4 * lane);
  #pragma unroll 1
  for (int s = 0; s < 8; ++s) {
    const int i = ibase + s;
    const float* xr = s_phi[wave * 8 + s];
    float sg[12];
    #pragma unroll
    for (int d = 0; d < 12; ++d) sg[d] = xr[d] > 0.f ? 1.f : -1.f;  // broadcast reads

    float4 o0 = bo0, o1 = bo1;
    #pragma unroll
    for (int d = 0; d < 12; ++d) {
      float4 wa = *(const float4*)&s_wt[d * 512 + 4 * lane];
      float4 wb = *(const float4*)&s_wt[d * 512 + 256 + 4 * lane];
      o0.x += sg[d] * wa.x; o0.y += sg[d] * wa.y; o0.z += sg[d] * wa.z; o0.w += sg[d] * wa.w;
      o1.x += sg[d] * wb.x; o1.y += sg[d] * wb.y; o1.z += sg[d] * wb.z; o1.w += sg[d] * wb.w;
    }
    *(float4*)(out + (size_t)i * 512 + 4 * lane)       = o0;
    *(float4*)(out + (size_t)i * 512 + 256 + 4 * lane) = o1;
  }

  // ---- Pass C: factorized softmax entropy; publish phi/psi rows
  float hacc = 0.f;
  #pragma unroll 1
  for (int s = 0; s < 8; ++s) {
    const int ws = wave * 8 + s;
    float xq[12];
    #pragma unroll
    for (int d = 0; d < 12; ++d) xq[d] = s_phi[ws][d];

    float hi = 0.f, lo = 0.f, ah = 0.f, al = 0.f;
    #pragma unroll
    for (int d = 0; d < 6; ++d) {
      int bh = (lane >> (5 - d)) & 1;
      hi += bh ? xq[d]     : -xq[d];
      lo += bh ? xq[6 + d] : -xq[6 + d];
      ah += fabsf(xq[d]);
      al += fabsf(xq[6 + d]);
    }
    float lhi = INVT2 * (hi - ah);   // <= 0, max over lanes == 0
    float llo = INVT2 * (lo - al);
    float ehi = __expf(lhi);
    float elo = __expf(llo);
    float Shi = ehi, Slo = elo;
    #pragma unroll
    for (int m = 1; m <= 32; m <<= 1) {
      Shi += __shfl_xor(Shi, m);
      Slo += __shfl_xor(Slo, m);
    }
    float phi = ehi / Shi;
    float psi = elo / Slo;
    float lnShi = __logf(Shi), lnSlo = __logf(Slo);
    hacc += phi * (lhi - lnShi) + psi * (llo - lnSlo);  // = -(H_hi + H_lo) contribution

    s_phi[ws][lane] = phi;   // overwrites the xp scratch (already consumed)
    s_psi[ws][lane] = psi;
  }
  #pragma unroll
  for (int m = 1; m <= 32; m <<= 1) hacc += __shfl_xor(hacc, m);
  if (lane == 0) atomicAdd(Csum, hacc);

  __syncthreads();   // publish s_phi/s_psi across waves

  // ---- Phase D: avg_prob partial P[j][l] = sum_s phi[s][j]*psi[s][l]
  // each thread owns a 4(j) x 2(l) code tile -> 8 accumulator registers
  const int jb = (t >> 5) * 4;   // 16 j-tiles of 4
  const int lb = (t & 31) * 2;   // 32 l-tiles of 2
  float a00 = 0.f, a01 = 0.f, a10 = 0.f, a11 = 0.f;
  float a20 = 0.f, a21 = 0.f, a30 = 0.f, a31 = 0.f;
  #pragma unroll 4
  for (int s = 0; s < 64; ++s) {
    float4 ph = *(const float4*)&s_phi[s][jb];
    float2 ps = *(const float2*)&s_psi[s][lb];
    a00 += ph.x * ps.x; a01 += ph.x * ps.y;
    a10 += ph.y * ps.x; a11 += ph.y * ps.y;
    a20 += ph.z * ps.x; a21 += ph.z * ps.y;
    a30 += ph.w * ps.x; a31 += ph.w * ps.y;
  }
  float* Pr = P + (size_t)blockIdx.x * 4096;
  *(float2*)&Pr[(jb + 0) * 64 + lb] = make_float2(a00, a01);
  *(float2*)&Pr[(jb + 1) * 64 + lb] = make_float2(a10, a11);
  *(float2*)&Pr[(jb + 2) * 64 + lb] = make_float2(a20, a21);
  *(float2*)&Pr[(jb + 3) * 64 + lb] = make_float2(a30, a31);
}

// -------- K2: reduce partials -> avg_prob, accumulate codebook entropy (exact, clipped)
__global__ __launch_bounds__(256) void k_reduce(const float* __restrict__ P,
                                                float* __restrict__ Esum) {
  __shared__ float red[16][17];
  __shared__ float ered[16];
  const int t = threadIdx.x;
  const int cl = t & 15, rg = t >> 4;
  const int c = blockIdx.x * 16 + cl;
  float s = 0.f;
  #pragma unroll
  for (int k = 0; k < 16; ++k) s += P[(size_t)(rg + k * 16) * 4096 + c];
  red[rg][cl] = s;
  __syncthreads();
  if (t < 16) {
    float tot = 0.f;
    #pragma unroll
    for (int r = 0; r < 16; ++r) tot += red[r][t];
    float pb = tot * (1.f / (float)NS);
    ered[t] = pb * __logf(fmaxf(pb, 1e-5f));   // p * log(clip(p, eps))
  }
  __syncthreads();
  if (t == 0) {
    float e = 0.f;
    #pragma unroll
    for (int r = 0; r < 16; ++r) e += ered[r];
    atomicAdd(Esum, e);
  }
}

// -------- K3: combine into aux_loss
__global__ void k_final(const float* __restrict__ Csum, const float* __restrict__ Esum,
                        float* __restrict__ aux) {
  if (threadIdx.x == 0) {
    float per_sample_entropy = -Csum[0] * (1.f / (float)NS);
    float codebook_entropy   = -Esum[0];
    aux[0] = 0.1f * (per_sample_entropy - codebook_entropy);
  }
}

extern "C" void kernel_launch(void* const* d_in, const int* in_sizes, int n_in,
                              void* d_out, int out_size, void* d_ws, size_t ws_size,
                              hipStream_t stream) {
  const float* x     = (const float*)d_in[0];
  const float* w_in  = (const float*)d_in[1];
  const float* b_in  = (const float*)d_in[2];
  const float* w_out = (const float*)d_in[3];
  const float* b_out = (const float*)d_in[4];
  float* out = (float*)d_out;

  float* P    = (float*)d_ws;                                    // 256*4096 f32 = 4 MB
  float* scal = (float*)((char*)d_ws + (size_t)NBLK * 4096 * 4); // {C_sum, E_sum}

  hipMemsetAsync(scal, 0, 2 * sizeof(float), stream);
  k_main<<<NBLK, 512, 0, stream>>>(x, w_in, b_in, w_out, b_out,
                                   out, out + NOUT, P, scal);
  k_reduce<<<256, 256, 0, stream>>>(P, scal + 1);
  k_final<<<1, 64, 0, stream>>>(scal, scal + 1, out + AUXO);
}

// Round 4
// 252.778 us; speedup vs baseline: 1.5015x; 1.5015x over previous
//
#include <hip/hip_runtime.h>
#include <hip/hip_bf16.h>

// LFQ forward fused kernels for MI355X (gfx950).
// Outputs in d_out (float32): out[16384*512], indices[16384] (as float), aux_loss[1]
// ws layout: P[256][4096] partial avg_prob sums (4 MB), then 2 scalars {C_sum, E_sum}

#define NS    16384      // samples = 4*4096
#define NOUT  (NS*512)   // 8388608
#define AUXO  (NOUT+NS)  // 8404992
#define INVT2 200.0f     // 2 * inv_temperature
#define NBLK  256        // K1 blocks; 64 samples each

// -------- K1: xp, indices, out-projection, factorized softmax entropy + avg_prob partials
// LDS = 24 + 24 + 16 + 16 = 80 KB exactly -> 2 blocks/CU (16 waves/CU).
// __launch_bounds__(512, 2): 128-VGPR cap. (512,4) forced 64 VGPRs -> massive spill (R3).
__global__ __launch_bounds__(512, 2) void k_main(
    const float* __restrict__ x,
    const float* __restrict__ w_in,  const float* __restrict__ b_in,
    const float* __restrict__ w_out, const float* __restrict__ b_out,
    float* __restrict__ out, float* __restrict__ idx_out,
    float* __restrict__ P, float* __restrict__ Csum) {

  __shared__ __align__(16) float s_wi[6144];     // w_in  row-major [d][512]
  __shared__ __align__(16) float s_wt[6144];     // w_out^T row-major [d][512]
  __shared__ __align__(16) float s_phi[64][64];  // rows: first hold xp[12], then phi[64]
  __shared__ __align__(16) float s_psi[64][64];

  const int t = threadIdx.x;

  // stage weights (row-major; lane mapping below is conflict-free without swizzle)
  #pragma unroll
  for (int k = 0; k < 12; ++k) {
    int f = t + k * 512;
    int d = f >> 9, e = f & 511;
    s_wi[f] = w_in[f];             // w_in is [12][512] row-major already
    s_wt[f] = w_out[e * 12 + d];   // transpose of w_out[512][12]
  }
  __syncthreads();

  const int wave = t >> 6, lane = t & 63;
  const int g = lane >> 4, sub = lane & 15;
  const int ibase = blockIdx.x * 64 + wave * 8;

  float bin[12];
  #pragma unroll
  for (int d = 0; d < 12; ++d) bin[d] = b_in[d];

  // ---- Pass A: projection-in, 16 lanes per sample, e = e4*64 + sub*4 (coalesced)
  #pragma unroll 1
  for (int bt = 0; bt < 2; ++bt) {
    const int i = ibase + bt * 4 + g;
    float4 xv[8];
    #pragma unroll
    for (int e4 = 0; e4 < 8; ++e4)
      xv[e4] = *(const float4*)(x + (size_t)i * 512 + e4 * 64 + sub * 4);

    float p[12];
    #pragma unroll
    for (int d = 0; d < 12; ++d) p[d] = 0.f;
    #pragma unroll
    for (int e4 = 0; e4 < 8; ++e4) {
      #pragma unroll
      for (int d = 0; d < 12; ++d) {
        float4 w4 = *(const float4*)&s_wi[d * 512 + e4 * 64 + sub * 4];
        p[d] += xv[e4].x * w4.x + xv[e4].y * w4.y + xv[e4].z * w4.z + xv[e4].w * w4.w;
      }
    }
    #pragma unroll
    for (int d = 0; d < 12; ++d) {
      #pragma unroll
      for (int m = 1; m <= 8; m <<= 1) p[d] += __shfl_xor(p[d], m, 16);
      p[d] += bin[d];
    }

    unsigned idx = 0u;
    #pragma unroll
    for (int d = 0; d < 12; ++d) idx |= (p[d] > 0.f ? 1u : 0u) << (11 - d);
    if (sub == 0) {
      idx_out[i] = (float)idx;
      #pragma unroll
      for (int d = 0; d < 12; ++d) s_phi[wave * 8 + bt * 4 + g][d] = p[d];
    }
    // same-wave LDS write->read below; lockstep + compiler lgkmcnt keeps order
  }

  // ---- Pass B: projection-out, all 64 lanes on one sample; e = 4*lane / 256+4*lane
  // -> two perfectly contiguous 1 KB wave stores per sample
  float4 bo0 = *(const float4*)(b_out + 4 * lane);
  float4 bo1 = *(const float4*)(b_out + 256 + 4 * lane);
  #pragma unroll 1
  for (int s = 0; s < 8; ++s) {
    const int i = ibase + s;
    const float* xr = s_phi[wave * 8 + s];
    float sg[12];
    #pragma unroll
    for (int d = 0; d < 12; ++d) sg[d] = xr[d] > 0.f ? 1.f : -1.f;  // broadcast reads

    float4 o0 = bo0, o1 = bo1;
    #pragma unroll
    for (int d = 0; d < 12; ++d) {
      float4 wa = *(const float4*)&s_wt[d * 512 + 4 * lane];
      float4 wb = *(const float4*)&s_wt[d * 512 + 256 + 4 * lane];
      o0.x += sg[d] * wa.x; o0.y += sg[d] * wa.y; o0.z += sg[d] * wa.z; o0.w += sg[d] * wa.w;
      o1.x += sg[d] * wb.x; o1.y += sg[d] * wb.y; o1.z += sg[d] * wb.z; o1.w += sg[d] * wb.w;
    }
    *(float4*)(out + (size_t)i * 512 + 4 * lane)       = o0;
    *(float4*)(out + (size_t)i * 512 + 256 + 4 * lane) = o1;
  }

  // ---- Pass C: factorized softmax entropy; publish phi/psi rows
  float hacc = 0.f;
  #pragma unroll 1
  for (int s = 0; s < 8; ++s) {
    const int ws = wave * 8 + s;
    float xq[12];
    #pragma unroll
    for (int d = 0; d < 12; ++d) xq[d] = s_phi[ws][d];

    float hi = 0.f, lo = 0.f, ah = 0.f, al = 0.f;
    #pragma unroll
    for (int d = 0; d < 6; ++d) {
      int bh = (lane >> (5 - d)) & 1;
      hi += bh ? xq[d]     : -xq[d];
      lo += bh ? xq[6 + d] : -xq[6 + d];
      ah += fabsf(xq[d]);
      al += fabsf(xq[6 + d]);
    }
    float lhi = INVT2 * (hi - ah);   // <= 0, max over lanes == 0
    float llo = INVT2 * (lo - al);
    float ehi = __expf(lhi);
    float elo = __expf(llo);
    float Shi = ehi, Slo = elo;
    #pragma unroll
    for (int m = 1; m <= 32; m <<= 1) {
      Shi += __shfl_xor(Shi, m);
      Slo += __shfl_xor(Slo, m);
    }
    float phi = ehi / Shi;
    float psi = elo / Slo;
    float lnShi = __logf(Shi), lnSlo = __logf(Slo);
    hacc += phi * (lhi - lnShi) + psi * (llo - lnSlo);  // = -(H_hi + H_lo) contribution

    s_phi[ws][lane] = phi;   // overwrites the xp scratch (already consumed)
    s_psi[ws][lane] = psi;
  }
  #pragma unroll
  for (int m = 1; m <= 32; m <<= 1) hacc += __shfl_xor(hacc, m);
  if (lane == 0) atomicAdd(Csum, hacc);

  __syncthreads();   // publish s_phi/s_psi across waves

  // ---- Phase D: avg_prob partial P[j][l] = sum_s phi[s][j]*psi[s][l]
  // each thread owns a 4(j) x 2(l) code tile -> 8 accumulator registers
  const int jb = (t >> 5) * 4;   // 16 j-tiles of 4
  const int lb = (t & 31) * 2;   // 32 l-tiles of 2
  float a00 = 0.f, a01 = 0.f, a10 = 0.f, a11 = 0.f;
  float a20 = 0.f, a21 = 0.f, a30 = 0.f, a31 = 0.f;
  #pragma unroll 4
  for (int s = 0; s < 64; ++s) {
    float4 ph = *(const float4*)&s_phi[s][jb];
    float2 ps = *(const float2*)&s_psi[s][lb];
    a00 += ph.x * ps.x; a01 += ph.x * ps.y;
    a10 += ph.y * ps.x; a11 += ph.y * ps.y;
    a20 += ph.z * ps.x; a21 += ph.z * ps.y;
    a30 += ph.w * ps.x; a31 += ph.w * ps.y;
  }
  float* Pr = P + (size_t)blockIdx.x * 4096;
  *(float2*)&Pr[(jb + 0) * 64 + lb] = make_float2(a00, a01);
  *(float2*)&Pr[(jb + 1) * 64 + lb] = make_float2(a10, a11);
  *(float2*)&Pr[(jb + 2) * 64 + lb] = make_float2(a20, a21);
  *(float2*)&Pr[(jb + 3) * 64 + lb] = make_float2(a30, a31);
}

// -------- K2: reduce partials -> avg_prob, accumulate codebook entropy (exact, clipped)
__global__ __launch_bounds__(256) void k_reduce(const float* __restrict__ P,
                                                float* __restrict__ Esum) {
  __shared__ float red[16][17];
  __shared__ float ered[16];
  const int t = threadIdx.x;
  const int cl = t & 15, rg = t >> 4;
  const int c = blockIdx.x * 16 + cl;
  float s = 0.f;
  #pragma unroll
  for (int k = 0; k < 16; ++k) s += P[(size_t)(rg + k * 16) * 4096 + c];
  red[rg][cl] = s;
  __syncthreads();
  if (t < 16) {
    float tot = 0.f;
    #pragma unroll
    for (int r = 0; r < 16; ++r) tot += red[r][t];
    float pb = tot * (1.f / (float)NS);
    ered[t] = pb * __logf(fmaxf(pb, 1e-5f));   // p * log(clip(p, eps))
  }
  __syncthreads();
  if (t == 0) {
    float e = 0.f;
    #pragma unroll
    for (int r = 0; r < 16; ++r) e += ered[r];
    atomicAdd(Esum, e);
  }
}

// -------- K3: combine into aux_loss
__global__ void k_final(const float* __restrict__ Csum, const float* __restrict__ Esum,
                        float* __restrict__ aux) {
  if (threadIdx.x == 0) {
    float per_sample_entropy = -Csum[0] * (1.f / (float)NS);
    float codebook_entropy   = -Esum[0];
    aux[0] = 0.1f * (per_sample_entropy - codebook_entropy);
  }
}

extern "C" void kernel_launch(void* const* d_in, const int* in_sizes, int n_in,
                              void* d_out, int out_size, void* d_ws, size_t ws_size,
                              hipStream_t stream) {
  const float* x     = (const float*)d_in[0];
  const float* w_in  = (const float*)d_in[1];
  const float* b_in  = (const float*)d_in[2];
  const float* w_out = (const float*)d_in[3];
  const float* b_out = (const float*)d_in[4];
  float* out = (float*)d_out;

  float* P    = (float*)d_ws;                                    // 256*4096 f32 = 4 MB
  float* scal = (float*)((char*)d_ws + (size_t)NBLK * 4096 * 4); // {C_sum, E_sum}

  hipMemsetAsync(scal, 0, 2 * sizeof(float), stream);
  k_main<<<NBLK, 512, 0, stream>>>(x, w_in, b_in, w_out, b_out,
                                   out, out + NOUT, P, scal);
  k_reduce<<<256, 256, 0, stream>>>(P, scal + 1);
  k_final<<<1, 64, 0, stream>>>(scal, scal + 1, out + AUXO);
}